// Round 13
// baseline (150.189 us; speedup 1.0000x reference)
//
#include <hip/hip_runtime.h>
#include <cmath>

#define M_ROWS  65536
#define D_DIM   64
#define K_CODES 4096

// d_out float offsets (z_q_st | indices | vq_loss | perplexity | z_q)
#define OFF_IDX  4194304
#define OFF_SCAL 4259840
#define OFF_ZQ   4259842

// fallback-path scratch regions inside d_out
#define IMG_OFF   (4u << 20)                 // codebook image (fallback path only)
#define CANDB_OFF 17039368u                  // == OFF_ZQ*4 : fallback cand64

// codebook chunk image: 128 codes, f16 HI only, 128 B/row, XOR-swizzled granules
#define CH_BYTES 16384
#define CH_QUADS 1024
#define NCHB_F   32                           // fused path: all 32 chunks per block
#define NSPLIT   4                            // fallback path K-split
#define NCHB     8

typedef _Float16 f16x8 __attribute__((ext_vector_type(8)));
typedef __attribute__((ext_vector_type(4))) float f32x4;
typedef unsigned long long u64;

__device__ __forceinline__ unsigned short f2h(float f) {    // RNE float->f16 bits
  _Float16 h = (_Float16)f;
  return __builtin_bit_cast(unsigned short, h);
}
__device__ __forceinline__ float h2f(unsigned short u) {
  return (float)__builtin_bit_cast(_Float16, u);
}
__device__ __forceinline__ unsigned int umin_(unsigned int a, unsigned int b) {
  return a < b ? a : b;
}
// second-min update: with invariant b1 <= b2, new b2 = median(old b1, b2, key)
__device__ __forceinline__ unsigned int med3_u32(unsigned int a, unsigned int b, unsigned int c) {
  unsigned int d;
  asm("v_med3_u32 %0, %1, %2, %3" : "=v"(d) : "v"(a), "v"(b), "v"(c));
  return d;
}

// async global->LDS (size must be literal)
__device__ __forceinline__ void gload_lds16(const void* g, void* l) {
  __builtin_amdgcn_global_load_lds((const __attribute__((address_space(1))) void*)g,
                                   (__attribute__((address_space(3))) void*)l, 16, 0, 0);
}
__device__ __forceinline__ void gload_lds4(const void* g, void* l) {
  __builtin_amdgcn_global_load_lds((const __attribute__((address_space(1))) void*)g,
                                   (__attribute__((address_space(3))) void*)l, 4, 0, 0);
}

// exact distance with the numpy-matched formula (verified r2..r10)
__device__ __forceinline__ float exact_dist(const float4* z4, float z2,
                                            const float* __restrict__ cb,
                                            const float* __restrict__ e2, int k) {
  const float4* ev = (const float4*)(cb + (size_t)k * 64);
  float4 a0 = make_float4(0.f, 0.f, 0.f, 0.f);
  float4 a1 = make_float4(0.f, 0.f, 0.f, 0.f);
  float4 a2 = make_float4(0.f, 0.f, 0.f, 0.f);
  float4 a3 = make_float4(0.f, 0.f, 0.f, 0.f);
#pragma unroll
  for (int q = 0; q < 4; ++q) {
    float4 e0 = ev[4 * q + 0], e1 = ev[4 * q + 1], e2v = ev[4 * q + 2], e3 = ev[4 * q + 3];
    a0.x = fmaf(z4[4 * q + 0].x, e0.x, a0.x); a0.y = fmaf(z4[4 * q + 0].y, e0.y, a0.y);
    a0.z = fmaf(z4[4 * q + 0].z, e0.z, a0.z); a0.w = fmaf(z4[4 * q + 0].w, e0.w, a0.w);
    a1.x = fmaf(z4[4 * q + 1].x, e1.x, a1.x); a1.y = fmaf(z4[4 * q + 1].y, e1.y, a1.y);
    a1.z = fmaf(z4[4 * q + 1].z, e1.z, a1.z); a1.w = fmaf(z4[4 * q + 1].w, e1.w, a1.w);
    a2.x = fmaf(z4[4 * q + 2].x, e2v.x, a2.x); a2.y = fmaf(z4[4 * q + 2].y, e2v.y, a2.y);
    a2.z = fmaf(z4[4 * q + 2].z, e2v.z, a2.z); a2.w = fmaf(z4[4 * q + 2].w, e2v.w, a2.w);
    a3.x = fmaf(z4[4 * q + 3].x, e3.x, a3.x); a3.y = fmaf(z4[4 * q + 3].y, e3.y, a3.y);
    a3.z = fmaf(z4[4 * q + 3].z, e3.z, a3.z); a3.w = fmaf(z4[4 * q + 3].w, e3.w, a3.w);
  }
  float d;
  {
#pragma clang fp contract(off)
    float sx = (a0.x + a1.x) + (a2.x + a3.x);
    float sy = (a0.y + a1.y) + (a2.y + a3.y);
    float sz = (a0.z + a1.z) + (a2.z + a3.z);
    float sw = (a0.w + a1.w) + (a2.w + a3.w);
    float dot = (sx + sy) + (sz + sw);
    float tt = z2 + e2[k];
    d = tt - 2.0f * dot;
  }
  return d;
}

__device__ __forceinline__ float exact_z2(const float4* z4) {
#pragma clang fp contract(off)
  float rr[8];
  {
    const float* f = (const float*)&z4[0];
#pragma unroll
    for (int j = 0; j < 8; ++j) rr[j] = f[j] * f[j];
  }
#pragma unroll
  for (int a = 1; a < 8; ++a) {
    const float* f = (const float*)&z4[2 * a];
#pragma unroll
    for (int j = 0; j < 8; ++j) rr[j] = rr[j] + f[j] * f[j];
  }
  return ((rr[0] + rr[1]) + (rr[2] + rr[3])) + ((rr[4] + rr[5]) + (rr[6] + rr[7]));
}

// float bits -> monotonic unsigned ordering (handles negatives)
__device__ __forceinline__ unsigned int ford(float f) {
  unsigned int b = __float_as_uint(f);
  return b ^ ((((int)b) >> 31) | 0x80000000u);
}

// ---------------------------------------------------------------------------
// K1: prep — f16 HI-only image (coalesced, LDS-swizzled granules) + e2/e2b
// (numpy-exact) fused. UNCHANGED (r9-proven).
// ---------------------------------------------------------------------------
__global__ void prep_kernel(const float* __restrict__ cb, char* __restrict__ img,
                            float* __restrict__ e2, float* __restrict__ e2b) {
  int t = blockIdx.x * 256 + threadIdx.x;   // 65536 threads, 4 elements each
  {
    int k  = t >> 4;
    int d0 = (t & 15) * 4;
    float4 f = ((const float4*)cb)[t];
    ushort4 hi;
    hi.x = f2h(f.x);
    hi.y = f2h(f.y);
    hi.z = f2h(f.z);
    hi.w = f2h(f.w);
    int c = k >> 7, r = k & 127;
    int g = d0 >> 3;
    int off = ((g + r) & 7) * 16 + (d0 & 7) * 2;
    char* base = img + (size_t)c * CH_BYTES + r * 128;
    *(ushort4*)(base + off) = hi;
  }
  if (t < K_CODES) {                         // blocks 0..15 also compute e2
    const float4* row = (const float4*)(cb + (size_t)t * D_DIM);
    float4 q[16];
#pragma unroll
    for (int i = 0; i < 16; ++i) q[i] = row[i];
    float s = exact_z2(q);
    e2[t] = s;
    e2b[t] = s + 32.0f;
  }
}

// ---------------------------------------------------------------------------
// K2-FUSED v5: identical per-thread work to r12 (78.6us), repartitioned into
// 256-thread blocks x 1024 (64 rows/block, 4 blocks/CU). Rationale: the fused
// kernel has a ~15us serial tail (selection+zq) per block; at 2 blocks/CU only
// one neighbor's distance loop covers it, at 4 blocks/CU three do (m114
// cross-block overlap). r8's occupancy-null was measured on the TAIL-LESS
// 3-kernel core — this is the first probe of block granularity on the fused
// kernel. Each wave still owns 16 rows x 4096 codes (same regs, same VALU).
// lb(256,4) keeps a 128-VGPR budget (r4 lesson: never squeeze to 32).
// ---------------------------------------------------------------------------
__global__ __launch_bounds__(256, 4)
void vq_full_kernel(const float* __restrict__ z_e,
                    const char* __restrict__ img,
                    const float* __restrict__ e2b,
                    const float* __restrict__ cb,
                    const float* __restrict__ e2,
                    float* __restrict__ out,
                    double* __restrict__ partials) {
  __shared__ union {
    uint4 q[2][CH_QUADS];            // 2 x 16 KB chunk double-buffer
    char raw[2][CH_BYTES];
    unsigned int cand[64 * 33];      // 8.4 KB, used only after the loop
  } sm;
  __shared__ float lds_e2[2][128];
  __shared__ int sidx[64];
  __shared__ double red[4];
  const int tid  = threadIdx.x;
  const int wave = tid >> 6, lane = tid & 63;   // 4 waves
  const int quad = lane >> 4, c16 = lane & 15;
  const int R0   = blockIdx.x * 64;

  // stage chunk 0 first so its latency hides under A-fragment build
  // (256 thr x 4 x 16B = 16 KB; dest = uniform base + lane*16 per call)
  {
    const uint4* src = (const uint4*)img;
#pragma unroll
    for (int i = 0; i < 4; ++i) gload_lds16(src + tid + i * 256, &sm.q[0][tid + i * 256]);
    if (tid < 128) gload_lds4(e2b + tid, &lds_e2[0][tid]);
  }

  // A-fragments: 1 row-tile (16 rows/wave) x k-halves, f16 hi only
  f16x8 zh[2];
  {
    int m = R0 + wave * 16 + c16;
#pragma unroll
    for (int s = 0; s < 2; ++s) {
      const float* zp = z_e + (size_t)m * 64 + s * 32 + quad * 8;
      float4 fa = ((const float4*)zp)[0];
      float4 fb = ((const float4*)zp)[1];
      float v[8] = {fa.x, fa.y, fa.z, fa.w, fb.x, fb.y, fb.z, fb.w};
      union { f16x8 v8; unsigned short e[8]; } H;
#pragma unroll
      for (int j = 0; j < 8; ++j) H.e[j] = f2h(-2.0f * v[j]);
      zh[s] = H.v8;
    }
  }

  unsigned int b1[4], b2[4];
#pragma unroll
  for (int r = 0; r < 4; ++r) { b1[r] = 0xFFFFFFFFu; b2[r] = 0xFFFFFFFFu; }

  const int swz0 = ((quad + c16) & 7) * 16;       // t-invariant swizzle offsets
  const int swz1 = ((quad + 4 + c16) & 7) * 16;

  __syncthreads();                                // drains vmcnt(0): chunk 0 ready

  int cur = 0;
  for (int c = 0; c < NCHB_F; ++c) {
    if (c + 1 < NCHB_F) {                         // next-chunk loads fly under compute
      const int nb = cur ^ 1;
      const uint4* src = (const uint4*)(img + (size_t)(c + 1) * CH_BYTES);
#pragma unroll
      for (int i = 0; i < 4; ++i) gload_lds16(src + tid + i * 256, &sm.q[nb][tid + i * 256]);
      if (tid < 128) gload_lds4(e2b + (c + 1) * 128 + tid, &lds_e2[nb][tid]);
    }

#pragma unroll 2
    for (int t = 0; t < 8; ++t) {
      const char* hb = sm.raw[cur] + (t * 16 + c16) * 128;
      f16x8 Bh0 = *(const f16x8*)(hb + swz0);
      f16x8 Bh1 = *(const f16x8*)(hb + swz1);
      float e2v = lds_e2[cur][t * 16 + c16];
      unsigned int tid8 = (unsigned int)(c * 8 + t);   // global 16-code tile id, 0..255
      f32x4 cvec = {e2v, e2v, e2v, e2v};

      f32x4 acc;
      acc = __builtin_amdgcn_mfma_f32_16x16x32_f16(zh[0], Bh0, cvec, 0, 0, 0);
      acc = __builtin_amdgcn_mfma_f32_16x16x32_f16(zh[1], Bh1, acc, 0, 0, 0);
#pragma unroll
      for (int r = 0; r < 4; ++r) {
        unsigned int key = (__float_as_uint(acc[r]) & 0xFFFFFF00u) | tid8;
        b2[r] = med3_u32(b1[r], b2[r], key);
        b1[r] = umin_(b1[r], key);
      }
    }
    __syncthreads();   // drains vmcnt(0): next buffer complete; fences LDS reads
    cur ^= 1;
  }

  // selection: per-row top-4 of 32 bucket mins (16 cols x {b1,b2})
  {
#pragma unroll
    for (int r = 0; r < 4; ++r) {
      int lr = wave * 16 + quad * 4 + r;   // C: col=lane&15, row=quad*4+reg
      sm.cand[lr * 33 + c16 * 2 + 0] = b1[r];
      sm.cand[lr * 33 + c16 * 2 + 1] = b2[r];
    }
  }
  __syncthreads();
  if (tid < 64) {
    unsigned int kk[4] = {0xFFFFFFFFu, 0xFFFFFFFFu, 0xFFFFFFFFu, 0xFFFFFFFFu};
    unsigned int vv[4] = {0, 0, 0, 0};
    for (int j = 0; j < 32; ++j) {
      unsigned int key = sm.cand[tid * 33 + j];
      if (key < kk[3]) {
        kk[3] = key;
        vv[3] = (key & 0xFFu) * 16 + (unsigned int)(j >> 1);  // k = tile*16 + col
        for (int p = 3; p > 0; --p)
          if (kk[p] < kk[p - 1]) {
            unsigned int a = kk[p]; kk[p] = kk[p - 1]; kk[p - 1] = a;
            unsigned int b = vv[p]; vv[p] = vv[p - 1]; vv[p - 1] = b;
          }
      }
    }
    const int row = R0 + tid;
    unsigned int key1 = kk[0] & 0xFFFFFF00u;
    unsigned int key2 = kk[1] & 0xFFFFFF00u;
    int bk;
    if ((key2 - key1) >= 2048u) {                 // >= 8 quanta: key winner exact
      bk = (int)vv[0];
    } else {                                      // ambiguous: exact eval of top-4
      const float4* zr = (const float4*)(z_e + (size_t)row * 64);
      float4 z4[16];
#pragma unroll
      for (int j = 0; j < 16; ++j) z4[j] = zr[j];
      float z2 = exact_z2(z4);
      float bd = INFINITY;
      bk = K_CODES;
#pragma unroll 1
      for (int ci = 0; ci < 4; ++ci) {
        int k = (int)vv[ci];
        float d = exact_dist(z4, z2, cb, e2, k);
        if (d < bd || (d == bd && k < bk)) { bd = d; bk = k; }
      }
    }
    sidx[tid] = bk;
    out[OFF_IDX + row] = (float)bk;
  }
  __syncthreads();

  // zq phase: 64 rows, 16 lanes/row, 4 passes of 16 rows
  double csum = 0.0;
#pragma unroll
  for (int p = 0; p < 4; ++p) {
    const int lr  = p * 16 + (tid >> 4);
    const int m   = R0 + lr;
    const int seg = tid & 15;
    const int k   = sidx[lr];
    float4 q = *(const float4*)(cb + (size_t)k * 64 + seg * 4);
    float4 z = *(const float4*)(z_e + (size_t)m * 64 + seg * 4);
    ((float4*)out)[(size_t)m * 16 + seg] = q;            // z_q_st
    float* d1 = out + OFF_ZQ + (size_t)m * 64 + seg * 4; // z_q (8B-aligned)
    ((float2*)d1)[0] = make_float2(q.x, q.y);
    ((float2*)d1)[1] = make_float2(q.z, q.w);
    float dx = z.x - q.x, dy = z.y - q.y, dz = z.z - q.z, dw = z.w - q.w;
    csum += (double)dx * dx + (double)dy * dy + (double)dz * dz + (double)dw * dw;
  }
#pragma unroll
  for (int off = 32; off > 0; off >>= 1) csum += __shfl_down(csum, off);
  if (lane == 0) red[wave] = csum;
  __syncthreads();
  if (tid == 0) {
    double s = 0.0;
#pragma unroll
    for (int w = 0; w < 4; ++w) s += red[w];
    partials[blockIdx.x] = s;
  }
}

// ---------------------------------------------------------------------------
// FALLBACK PATH (small d_ws): round-8 proven kernels, verbatim.
// ---------------------------------------------------------------------------
__global__ __launch_bounds__(512, 4)
void vq_mfma_kernel(const float* __restrict__ z_e,
                    const char* __restrict__ img,
                    const float* __restrict__ e2b,
                    u64* __restrict__ cand64) {
  __shared__ union {
    uint4 q[2][CH_QUADS];
    char raw[2][CH_BYTES];
    unsigned int cand[256 * 33];
  } sm;
  __shared__ float lds_e2[2][128];
  const int tid  = threadIdx.x;
  const int wave = tid >> 6, lane = tid & 63;
  const int quad = lane >> 4, c16 = lane & 15;
  const int rb   = blockIdx.x >> 2;
  const int sp   = blockIdx.x & 3;
  const int mb   = rb * 256 + wave * 32;

  {
    const uint4* src = (const uint4*)(img + (size_t)(sp * NCHB + 0) * CH_BYTES);
    gload_lds16(src + tid, &sm.q[0][tid]);
    gload_lds16(src + tid + 512, &sm.q[0][tid + 512]);
    if (tid < 128) gload_lds4(e2b + sp * 1024 + 0 * 128 + tid, &lds_e2[0][tid]);
  }

  f16x8 zh[2][2];
#pragma unroll
  for (int mt = 0; mt < 2; ++mt) {
    int m = mb + mt * 16 + c16;
#pragma unroll
    for (int s = 0; s < 2; ++s) {
      const float* zp = z_e + (size_t)m * 64 + s * 32 + quad * 8;
      float4 fa = ((const float4*)zp)[0];
      float4 fb = ((const float4*)zp)[1];
      float v[8] = {fa.x, fa.y, fa.z, fa.w, fb.x, fb.y, fb.z, fb.w};
      union { f16x8 v8; unsigned short e[8]; } H;
#pragma unroll
      for (int j = 0; j < 8; ++j) H.e[j] = f2h(-2.0f * v[j]);
      zh[mt][s] = H.v8;
    }
  }

  unsigned int b1[2][4], b2[2][4];
#pragma unroll
  for (int mt = 0; mt < 2; ++mt)
#pragma unroll
    for (int r = 0; r < 4; ++r) { b1[mt][r] = 0xFFFFFFFFu; b2[mt][r] = 0xFFFFFFFFu; }

  const int swz0 = ((quad + c16) & 7) * 16;
  const int swz1 = ((quad + 4 + c16) & 7) * 16;

  __syncthreads();

  int cur = 0;
  for (int c = 0; c < NCHB; ++c) {
    if (c + 1 < NCHB) {
      const int nb = cur ^ 1;
      const uint4* src = (const uint4*)(img + (size_t)(sp * NCHB + c + 1) * CH_BYTES);
      gload_lds16(src + tid, &sm.q[nb][tid]);
      gload_lds16(src + tid + 512, &sm.q[nb][tid + 512]);
      if (tid < 128) gload_lds4(e2b + sp * 1024 + (c + 1) * 128 + tid, &lds_e2[nb][tid]);
    }

#pragma unroll 1
    for (int t = 0; t < 8; ++t) {
      const char* hb = sm.raw[cur] + (t * 16 + c16) * 128;
      f16x8 Bh0 = *(const f16x8*)(hb + swz0);
      f16x8 Bh1 = *(const f16x8*)(hb + swz1);
      float e2v = lds_e2[cur][t * 16 + c16];
      unsigned int tid8 = (unsigned int)(sp * 64 + c * 8 + t);
      f32x4 cvec = {e2v, e2v, e2v, e2v};

#pragma unroll
      for (int mt = 0; mt < 2; ++mt) {
        f32x4 acc;
        acc = __builtin_amdgcn_mfma_f32_16x16x32_f16(zh[mt][0], Bh0, cvec, 0, 0, 0);
        acc = __builtin_amdgcn_mfma_f32_16x16x32_f16(zh[mt][1], Bh1, acc, 0, 0, 0);
#pragma unroll
        for (int r = 0; r < 4; ++r) {
          unsigned int key = (__float_as_uint(acc[r]) & 0xFFFFFF00u) | tid8;
          b2[mt][r] = med3_u32(b1[mt][r], b2[mt][r], key);
          b1[mt][r] = umin_(b1[mt][r], key);
        }
      }
    }
    __syncthreads();
    cur ^= 1;
  }

  __syncthreads();
  {
#pragma unroll
    for (int mt = 0; mt < 2; ++mt)
#pragma unroll
      for (int r = 0; r < 4; ++r) {
        int lr = wave * 32 + mt * 16 + quad * 4 + r;
        sm.cand[lr * 33 + c16 * 2 + 0] = b1[mt][r];
        sm.cand[lr * 33 + c16 * 2 + 1] = b2[mt][r];
      }
  }
  __syncthreads();
  if (tid < 256) {
    unsigned int kk[4] = {0xFFFFFFFFu, 0xFFFFFFFFu, 0xFFFFFFFFu, 0xFFFFFFFFu};
    unsigned int vv[4] = {0, 0, 0, 0};
    for (int j = 0; j < 32; ++j) {
      unsigned int key = sm.cand[tid * 33 + j];
      if (key < kk[3]) {
        kk[3] = key;
        vv[3] = (key & 0xFFu) * 16 + (unsigned int)(j >> 1);
        for (int p = 3; p > 0; --p)
          if (kk[p] < kk[p - 1]) {
            unsigned int a = kk[p]; kk[p] = kk[p - 1]; kk[p - 1] = a;
            unsigned int b = vv[p]; vv[p] = vv[p - 1]; vv[p - 1] = b;
          }
      }
    }
    int grow = rb * 256 + tid;
#pragma unroll
    for (int i = 0; i < 4; ++i)
      cand64[(size_t)grow * 16 + sp * 4 + i] = ((u64)kk[i] << 32) | (u64)vv[i];
  }
}

__device__ __forceinline__ void pick_scan4(const u64* __restrict__ cand64,
                                           int row, int part, u64& s1, u64& s2) {
  s1 = ~0ull; s2 = ~0ull;
  const u64* cp = cand64 + (size_t)row * 16 + part * 4;
#pragma unroll
  for (int j = 0; j < 4; ++j) {
    u64 v = cp[j];
    if (v < s1) { s2 = s1; s1 = v; }
    else if (v < s2) s2 = v;
  }
#pragma unroll
  for (int m = 1; m <= 2; m <<= 1) {
    u64 o1 = __shfl_xor(s1, m);
    u64 o2 = __shfl_xor(s2, m);
    u64 hi  = s1 > o1 ? s1 : o1;
    u64 lo2 = s2 < o2 ? s2 : o2;
    s1 = s1 < o1 ? s1 : o1;
    s2 = hi < lo2 ? hi : lo2;
  }
}

__device__ __forceinline__ int pick_exact16(const float* __restrict__ z_e,
                                            const float* __restrict__ cb,
                                            const float* __restrict__ e2,
                                            const u64* __restrict__ cand64,
                                            int row, int lane16) {
  const int k = (int)(unsigned int)(cand64[(size_t)row * 16 + lane16] & 0xFFFFFFFFu);
  const float4* zr = (const float4*)(z_e + (size_t)row * 64);
  float4 z4[16];
#pragma unroll
  for (int j = 0; j < 16; ++j) z4[j] = zr[j];
  float z2 = exact_z2(z4);
  float d = exact_dist(z4, z2, cb, e2, k);
  u64 kk = ((u64)ford(d) << 32) | (unsigned int)k;
#pragma unroll
  for (int m = 1; m <= 8; m <<= 1) {
    u64 o = __shfl_xor(kk, m);
    kk = o < kk ? o : kk;
  }
  return (int)(unsigned int)(kk & 0xFFFFFFFFu);
}

__global__ __launch_bounds__(256)
void pick_kernel(const float* __restrict__ z_e, const float* __restrict__ cb,
                 const float* __restrict__ e2, const u64* __restrict__ cand64,
                 float* __restrict__ out) {
  __shared__ int list[64];
  __shared__ int lcnt;
  const int tid = threadIdx.x;
  const int R0  = blockIdx.x * 64;
  if (tid == 0) lcnt = 0;
  __syncthreads();

  {
    const int row = R0 + (tid >> 2);
    u64 s1, s2;
    pick_scan4(cand64, row, tid & 3, s1, s2);
    if ((tid & 3) == 0) {
      unsigned int key1 = (unsigned int)(s1 >> 32) & 0xFFFFFF00u;
      unsigned int key2 = (unsigned int)(s2 >> 32) & 0xFFFFFF00u;
      if ((key2 - key1) >= 2048u) {
        out[OFF_IDX + row] = (float)(unsigned int)(s1 & 0xFFFFFFFFu);
      } else {
        list[atomicAdd(&lcnt, 1)] = row - R0;
      }
    }
  }
  __syncthreads();

  const int n = lcnt;
  const int lane16 = tid & 15;
  for (int g = tid >> 4; g < n; g += 16) {
    const int row = R0 + list[g];
    int bk = pick_exact16(z_e, cb, e2, cand64, row, lane16);
    if (lane16 == 0) out[OFF_IDX + row] = (float)bk;
  }
}

__global__ __launch_bounds__(256)
void zq_kernel(const float* __restrict__ z_e, const float* __restrict__ cb,
               float* __restrict__ out, double* __restrict__ partials) {
  const int tid = threadIdx.x;
  const int t   = blockIdx.x * 256 + tid;
  const int m   = t >> 4, seg = t & 15;

  int k = (int)out[OFF_IDX + m];
  float4 q = *(const float4*)(cb + (size_t)k * 64 + seg * 4);
  float4 z = *(const float4*)(z_e + (size_t)m * 64 + seg * 4);

  ((float4*)out)[(size_t)m * 16 + seg] = q;
  float* d1 = out + OFF_ZQ + (size_t)m * 64 + seg * 4;
  ((float2*)d1)[0] = make_float2(q.x, q.y);
  ((float2*)d1)[1] = make_float2(q.z, q.w);

  float dx = z.x - q.x, dy = z.y - q.y, dz = z.z - q.z, dw = z.w - q.w;
  double csum = (double)dx * dx + (double)dy * dy + (double)dz * dz + (double)dw * dw;
#pragma unroll
  for (int off = 32; off > 0; off >>= 1) csum += __shfl_down(csum, off);
  if ((tid & 63) == 0) partials[blockIdx.x * 4 + (tid >> 6)] = csum;
}

// ---------------------------------------------------------------------------
// K5: vq_loss (sum of n partials) + perplexity — 1024 threads
// ---------------------------------------------------------------------------
__global__ void finalize_kernel(const float* __restrict__ ema,
                                const double* __restrict__ partials, int n,
                                float* __restrict__ out) {
  __shared__ double red[1024];
  const int t = threadIdx.x;

  double cs = 0.0;
  for (int i = t; i < n; i += 1024) cs += partials[i];
  red[t] = cs;
  __syncthreads();
  for (int off = 512; off > 0; off >>= 1) {
    if (t < off) red[t] += red[t + off];
    __syncthreads();
  }
  double commit = red[0];
  __syncthreads();

  double s = 0.0;
  for (int i = t; i < K_CODES; i += 1024) s += (double)(ema[i] + 1e-10f);
  red[t] = s;
  __syncthreads();
  for (int off = 512; off > 0; off >>= 1) {
    if (t < off) red[t] += red[t + off];
    __syncthreads();
  }
  double S = red[0];
  __syncthreads();

  double h = 0.0;
  for (int i = t; i < K_CODES; i += 1024) {
    float p = (float)((ema[i] + 1e-10f) / (float)S);
    h += (double)(p * logf(p));
  }
  red[t] = h;
  __syncthreads();
  for (int off = 512; off > 0; off >>= 1) {
    if (t < off) red[t] += red[t + off];
    __syncthreads();
  }

  if (t == 0) {
    out[OFF_SCAL]     = 0.25f * (float)(commit / (double)((size_t)M_ROWS * (size_t)D_DIM));
    out[OFF_SCAL + 1] = expf((float)(-red[0]));
  }
}

extern "C" void kernel_launch(void* const* d_in, const int* in_sizes, int n_in,
                              void* d_out, int out_size, void* d_ws, size_t ws_size,
                              hipStream_t stream) {
  (void)in_sizes; (void)n_in; (void)out_size;
  const float* z_e = (const float*)d_in[0];
  const float* cb  = (const float*)d_in[1];
  const float* ema = (const float*)d_in[2];
  float* out = (float*)d_out;

  // ws layout: e2 @0 (16K) | e2b @16K (16K) | partials @32K (128K) | img @160K (512K)
  float*  e2       = (float*)d_ws;
  float*  e2b      = (float*)((char*)d_ws + 16384);
  double* partials = (double*)((char*)d_ws + 32768);
  const size_t fused_need = 163840 + 524288;            // 672 KB

  if (ws_size >= fused_need) {
    char* img = (char*)d_ws + 163840;                   // img in ws: no alias with z_q_st
    prep_kernel<<<(K_CODES * D_DIM / 4) / 256, 256, 0, stream>>>(cb, img, e2, e2b);
    vq_full_kernel<<<M_ROWS / 64, 256, 0, stream>>>(z_e, img, e2b, cb, e2, out, partials);
    finalize_kernel<<<1, 1024, 0, stream>>>(ema, partials, M_ROWS / 64, out);
  } else {
    // fallback: round-8 three-kernel path; img + cand64 scratched inside d_out
    char* img = (char*)d_out + IMG_OFF;
    u64* cand64 = (u64*)((char*)d_out + CANDB_OFF);
    prep_kernel<<<(K_CODES * D_DIM / 4) / 256, 256, 0, stream>>>(cb, img, e2, e2b);
    vq_mfma_kernel<<<(M_ROWS / 256) * NSPLIT, 512, 0, stream>>>(z_e, img, e2b, cand64);
    pick_kernel<<<M_ROWS / 64, 256, 0, stream>>>(z_e, cb, e2, cand64, out);
    zq_kernel<<<M_ROWS * 16 / 256, 256, 0, stream>>>(z_e, cb, out, partials);
    finalize_kernel<<<1, 1024, 0, stream>>>(ema, partials, 16384, out);
  }
}

// Round 14
// 146.799 us; speedup vs baseline: 1.0231x; 1.0231x over previous
//
#include <hip/hip_runtime.h>
#include <cmath>

#define M_ROWS  65536
#define D_DIM   64
#define K_CODES 4096

// d_out float offsets (z_q_st | indices | vq_loss | perplexity | z_q)
#define OFF_IDX  4194304
#define OFF_SCAL 4259840
#define OFF_ZQ   4259842

// fallback-path scratch regions inside d_out
#define IMG_OFF   (4u << 20)                 // codebook image (fallback path only)
#define CANDB_OFF 17039368u                  // == OFF_ZQ*4 : fallback cand64

// codebook chunk image: 128 codes, f16 HI only, 128 B/row, XOR-swizzled granules
#define CH_BYTES 16384
#define CH_QUADS 1024
#define NCHB_F   32                           // fused path: all 32 chunks per block
#define NSPLIT   4                            // fallback path K-split
#define NCHB     8

typedef _Float16 f16x8 __attribute__((ext_vector_type(8)));
typedef __attribute__((ext_vector_type(4))) float f32x4;
typedef unsigned long long u64;

__device__ __forceinline__ unsigned short f2h(float f) {    // RNE float->f16 bits
  _Float16 h = (_Float16)f;
  return __builtin_bit_cast(unsigned short, h);
}
__device__ __forceinline__ float h2f(unsigned short u) {
  return (float)__builtin_bit_cast(_Float16, u);
}
__device__ __forceinline__ unsigned int umin_(unsigned int a, unsigned int b) {
  return a < b ? a : b;
}
// second-min update: with invariant b1 <= b2, new b2 = median(old b1, b2, key)
__device__ __forceinline__ unsigned int med3_u32(unsigned int a, unsigned int b, unsigned int c) {
  unsigned int d;
  asm("v_med3_u32 %0, %1, %2, %3" : "=v"(d) : "v"(a), "v"(b), "v"(c));
  return d;
}

// async global->LDS (size must be literal)
__device__ __forceinline__ void gload_lds16(const void* g, void* l) {
  __builtin_amdgcn_global_load_lds((const __attribute__((address_space(1))) void*)g,
                                   (__attribute__((address_space(3))) void*)l, 16, 0, 0);
}
__device__ __forceinline__ void gload_lds4(const void* g, void* l) {
  __builtin_amdgcn_global_load_lds((const __attribute__((address_space(1))) void*)g,
                                   (__attribute__((address_space(3))) void*)l, 4, 0, 0);
}

// exact distance with the numpy-matched formula (verified r2..r10)
__device__ __forceinline__ float exact_dist(const float4* z4, float z2,
                                            const float* __restrict__ cb,
                                            const float* __restrict__ e2, int k) {
  const float4* ev = (const float4*)(cb + (size_t)k * 64);
  float4 a0 = make_float4(0.f, 0.f, 0.f, 0.f);
  float4 a1 = make_float4(0.f, 0.f, 0.f, 0.f);
  float4 a2 = make_float4(0.f, 0.f, 0.f, 0.f);
  float4 a3 = make_float4(0.f, 0.f, 0.f, 0.f);
#pragma unroll
  for (int q = 0; q < 4; ++q) {
    float4 e0 = ev[4 * q + 0], e1 = ev[4 * q + 1], e2v = ev[4 * q + 2], e3 = ev[4 * q + 3];
    a0.x = fmaf(z4[4 * q + 0].x, e0.x, a0.x); a0.y = fmaf(z4[4 * q + 0].y, e0.y, a0.y);
    a0.z = fmaf(z4[4 * q + 0].z, e0.z, a0.z); a0.w = fmaf(z4[4 * q + 0].w, e0.w, a0.w);
    a1.x = fmaf(z4[4 * q + 1].x, e1.x, a1.x); a1.y = fmaf(z4[4 * q + 1].y, e1.y, a1.y);
    a1.z = fmaf(z4[4 * q + 1].z, e1.z, a1.z); a1.w = fmaf(z4[4 * q + 1].w, e1.w, a1.w);
    a2.x = fmaf(z4[4 * q + 2].x, e2v.x, a2.x); a2.y = fmaf(z4[4 * q + 2].y, e2v.y, a2.y);
    a2.z = fmaf(z4[4 * q + 2].z, e2v.z, a2.z); a2.w = fmaf(z4[4 * q + 2].w, e2v.w, a2.w);
    a3.x = fmaf(z4[4 * q + 3].x, e3.x, a3.x); a3.y = fmaf(z4[4 * q + 3].y, e3.y, a3.y);
    a3.z = fmaf(z4[4 * q + 3].z, e3.z, a3.z); a3.w = fmaf(z4[4 * q + 3].w, e3.w, a3.w);
  }
  float d;
  {
#pragma clang fp contract(off)
    float sx = (a0.x + a1.x) + (a2.x + a3.x);
    float sy = (a0.y + a1.y) + (a2.y + a3.y);
    float sz = (a0.z + a1.z) + (a2.z + a3.z);
    float sw = (a0.w + a1.w) + (a2.w + a3.w);
    float dot = (sx + sy) + (sz + sw);
    float tt = z2 + e2[k];
    d = tt - 2.0f * dot;
  }
  return d;
}

__device__ __forceinline__ float exact_z2(const float4* z4) {
#pragma clang fp contract(off)
  float rr[8];
  {
    const float* f = (const float*)&z4[0];
#pragma unroll
    for (int j = 0; j < 8; ++j) rr[j] = f[j] * f[j];
  }
#pragma unroll
  for (int a = 1; a < 8; ++a) {
    const float* f = (const float*)&z4[2 * a];
#pragma unroll
    for (int j = 0; j < 8; ++j) rr[j] = rr[j] + f[j] * f[j];
  }
  return ((rr[0] + rr[1]) + (rr[2] + rr[3])) + ((rr[4] + rr[5]) + (rr[6] + rr[7]));
}

// float bits -> monotonic unsigned ordering (handles negatives)
__device__ __forceinline__ unsigned int ford(float f) {
  unsigned int b = __float_as_uint(f);
  return b ^ ((((int)b) >> 31) | 0x80000000u);
}

// ---------------------------------------------------------------------------
// K1: prep — f16 HI-only image (coalesced, LDS-swizzled granules) + e2/e2b
// (numpy-exact) fused. r9-proven version.
// ---------------------------------------------------------------------------
__global__ void prep_kernel(const float* __restrict__ cb, char* __restrict__ img,
                            float* __restrict__ e2, float* __restrict__ e2b) {
  int t = blockIdx.x * 256 + threadIdx.x;   // 65536 threads, 4 elements each
  {
    int k  = t >> 4;
    int d0 = (t & 15) * 4;
    float4 f = ((const float4*)cb)[t];
    ushort4 hi;
    hi.x = f2h(f.x);
    hi.y = f2h(f.y);
    hi.z = f2h(f.z);
    hi.w = f2h(f.w);
    int c = k >> 7, r = k & 127;
    int g = d0 >> 3;
    int off = ((g + r) & 7) * 16 + (d0 & 7) * 2;
    char* base = img + (size_t)c * CH_BYTES + r * 128;
    *(ushort4*)(base + off) = hi;
  }
  if (t < K_CODES) {                         // blocks 0..15 also compute e2
    const float4* row = (const float4*)(cb + (size_t)t * D_DIM);
    float4 q[16];
#pragma unroll
    for (int i = 0; i < 16; ++i) q[i] = row[i];
    float s = exact_z2(q);
    e2[t] = s;
    e2b[t] = s + 32.0f;
  }
}

// ---------------------------------------------------------------------------
// K2-FUSED (SESSION-BEST, r12 = 146.9us total): r9's 79us body + unroll 2.
// PLATEAU NOTES (8 structural probes, r3-r13): distance core is pinned at
// ~64us by per-CU issue throughput + the 2-phase barrier drain; occupancy,
// tile shape, unroll depth, staging style, and block granularity are all
// measured-null. Do NOT: force lb waves>4 (r4 spill), full-unroll t-loop
// (r10), last-block finalize w/ threadfence (r11), direct-L2 B reads (r3).
// ---------------------------------------------------------------------------
__global__ __launch_bounds__(512, 4)
void vq_full_kernel(const float* __restrict__ z_e,
                    const char* __restrict__ img,
                    const float* __restrict__ e2b,
                    const float* __restrict__ cb,
                    const float* __restrict__ e2,
                    float* __restrict__ out,
                    double* __restrict__ partials) {
  __shared__ union {
    uint4 q[2][CH_QUADS];            // 2 x 16 KB chunk double-buffer
    char raw[2][CH_BYTES];
    unsigned int cand[128 * 33];     // 16.9 KB, used only after the loop
  } sm;
  __shared__ float lds_e2[2][128];
  __shared__ int sidx[128];
  __shared__ double red[8];
  const int tid  = threadIdx.x;
  const int wave = tid >> 6, lane = tid & 63;
  const int quad = lane >> 4, c16 = lane & 15;
  const int R0   = blockIdx.x * 128;

  // stage chunk 0 first so its latency hides under A-fragment build
  {
    const uint4* src = (const uint4*)img;
    gload_lds16(src + tid, &sm.q[0][tid]);
    gload_lds16(src + tid + 512, &sm.q[0][tid + 512]);
    if (tid < 128) gload_lds4(e2b + tid, &lds_e2[0][tid]);
  }

  // A-fragments: 1 row-tile (16 rows/wave) x k-halves, f16 hi only
  f16x8 zh[2];
  {
    int m = R0 + wave * 16 + c16;
#pragma unroll
    for (int s = 0; s < 2; ++s) {
      const float* zp = z_e + (size_t)m * 64 + s * 32 + quad * 8;
      float4 fa = ((const float4*)zp)[0];
      float4 fb = ((const float4*)zp)[1];
      float v[8] = {fa.x, fa.y, fa.z, fa.w, fb.x, fb.y, fb.z, fb.w};
      union { f16x8 v8; unsigned short e[8]; } H;
#pragma unroll
      for (int j = 0; j < 8; ++j) H.e[j] = f2h(-2.0f * v[j]);
      zh[s] = H.v8;
    }
  }

  unsigned int b1[4], b2[4];
#pragma unroll
  for (int r = 0; r < 4; ++r) { b1[r] = 0xFFFFFFFFu; b2[r] = 0xFFFFFFFFu; }

  const int swz0 = ((quad + c16) & 7) * 16;       // t-invariant swizzle offsets
  const int swz1 = ((quad + 4 + c16) & 7) * 16;

  __syncthreads();                                // drains vmcnt(0): chunk 0 ready

  int cur = 0;
  for (int c = 0; c < NCHB_F; ++c) {
    if (c + 1 < NCHB_F) {                         // next-chunk loads fly under compute
      const int nb = cur ^ 1;
      const uint4* src = (const uint4*)(img + (size_t)(c + 1) * CH_BYTES);
      gload_lds16(src + tid, &sm.q[nb][tid]);
      gload_lds16(src + tid + 512, &sm.q[nb][tid + 512]);
      if (tid < 128) gload_lds4(e2b + (c + 1) * 128 + tid, &lds_e2[nb][tid]);
    }

#pragma unroll 2
    for (int t = 0; t < 8; ++t) {
      const char* hb = sm.raw[cur] + (t * 16 + c16) * 128;
      f16x8 Bh0 = *(const f16x8*)(hb + swz0);
      f16x8 Bh1 = *(const f16x8*)(hb + swz1);
      float e2v = lds_e2[cur][t * 16 + c16];
      unsigned int tid8 = (unsigned int)(c * 8 + t);   // global 16-code tile id, 0..255
      f32x4 cvec = {e2v, e2v, e2v, e2v};

      f32x4 acc;
      acc = __builtin_amdgcn_mfma_f32_16x16x32_f16(zh[0], Bh0, cvec, 0, 0, 0);
      acc = __builtin_amdgcn_mfma_f32_16x16x32_f16(zh[1], Bh1, acc, 0, 0, 0);
#pragma unroll
      for (int r = 0; r < 4; ++r) {
        unsigned int key = (__float_as_uint(acc[r]) & 0xFFFFFF00u) | tid8;
        b2[r] = med3_u32(b1[r], b2[r], key);
        b1[r] = umin_(b1[r], key);
      }
    }
    __syncthreads();   // drains vmcnt(0): next buffer complete; fences LDS reads
    cur ^= 1;
  }

  // selection: per-row top-4 of 32 bucket mins (16 cols x {b1,b2})
  {
#pragma unroll
    for (int r = 0; r < 4; ++r) {
      int lr = wave * 16 + quad * 4 + r;   // C: col=lane&15, row=quad*4+reg
      sm.cand[lr * 33 + c16 * 2 + 0] = b1[r];
      sm.cand[lr * 33 + c16 * 2 + 1] = b2[r];
    }
  }
  __syncthreads();
  if (tid < 128) {
    unsigned int kk[4] = {0xFFFFFFFFu, 0xFFFFFFFFu, 0xFFFFFFFFu, 0xFFFFFFFFu};
    unsigned int vv[4] = {0, 0, 0, 0};
    for (int j = 0; j < 32; ++j) {
      unsigned int key = sm.cand[tid * 33 + j];
      if (key < kk[3]) {
        kk[3] = key;
        vv[3] = (key & 0xFFu) * 16 + (unsigned int)(j >> 1);  // k = tile*16 + col
        for (int p = 3; p > 0; --p)
          if (kk[p] < kk[p - 1]) {
            unsigned int a = kk[p]; kk[p] = kk[p - 1]; kk[p - 1] = a;
            unsigned int b = vv[p]; vv[p] = vv[p - 1]; vv[p - 1] = b;
          }
      }
    }
    const int row = R0 + tid;
    unsigned int key1 = kk[0] & 0xFFFFFF00u;
    unsigned int key2 = kk[1] & 0xFFFFFF00u;
    int bk;
    if ((key2 - key1) >= 2048u) {                 // >= 8 quanta: key winner exact
      bk = (int)vv[0];
    } else {                                      // ambiguous: exact eval of top-4
      const float4* zr = (const float4*)(z_e + (size_t)row * 64);
      float4 z4[16];
#pragma unroll
      for (int j = 0; j < 16; ++j) z4[j] = zr[j];
      float z2 = exact_z2(z4);
      float bd = INFINITY;
      bk = K_CODES;
#pragma unroll 1
      for (int ci = 0; ci < 4; ++ci) {
        int k = (int)vv[ci];
        float d = exact_dist(z4, z2, cb, e2, k);
        if (d < bd || (d == bd && k < bk)) { bd = d; bk = k; }
      }
    }
    sidx[tid] = bk;
    out[OFF_IDX + row] = (float)bk;
  }
  __syncthreads();

  // zq phase: 128 rows, 16 lanes/row, 4 passes of 32 rows
  double csum = 0.0;
#pragma unroll
  for (int p = 0; p < 4; ++p) {
    const int lr  = p * 32 + (tid >> 4);
    const int m   = R0 + lr;
    const int seg = tid & 15;
    const int k   = sidx[lr];
    float4 q = *(const float4*)(cb + (size_t)k * 64 + seg * 4);
    float4 z = *(const float4*)(z_e + (size_t)m * 64 + seg * 4);
    ((float4*)out)[(size_t)m * 16 + seg] = q;            // z_q_st
    float* d1 = out + OFF_ZQ + (size_t)m * 64 + seg * 4; // z_q (8B-aligned)
    ((float2*)d1)[0] = make_float2(q.x, q.y);
    ((float2*)d1)[1] = make_float2(q.z, q.w);
    float dx = z.x - q.x, dy = z.y - q.y, dz = z.z - q.z, dw = z.w - q.w;
    csum += (double)dx * dx + (double)dy * dy + (double)dz * dz + (double)dw * dw;
  }
#pragma unroll
  for (int off = 32; off > 0; off >>= 1) csum += __shfl_down(csum, off);
  if (lane == 0) red[wave] = csum;
  __syncthreads();
  if (tid == 0) {
    double s = 0.0;
#pragma unroll
    for (int w = 0; w < 8; ++w) s += red[w];
    partials[blockIdx.x] = s;
  }
}

// ---------------------------------------------------------------------------
// FALLBACK PATH (small d_ws): round-8 proven kernels, verbatim.
// ---------------------------------------------------------------------------
__global__ __launch_bounds__(512, 4)
void vq_mfma_kernel(const float* __restrict__ z_e,
                    const char* __restrict__ img,
                    const float* __restrict__ e2b,
                    u64* __restrict__ cand64) {
  __shared__ union {
    uint4 q[2][CH_QUADS];
    char raw[2][CH_BYTES];
    unsigned int cand[256 * 33];
  } sm;
  __shared__ float lds_e2[2][128];
  const int tid  = threadIdx.x;
  const int wave = tid >> 6, lane = tid & 63;
  const int quad = lane >> 4, c16 = lane & 15;
  const int rb   = blockIdx.x >> 2;
  const int sp   = blockIdx.x & 3;
  const int mb   = rb * 256 + wave * 32;

  {
    const uint4* src = (const uint4*)(img + (size_t)(sp * NCHB + 0) * CH_BYTES);
    gload_lds16(src + tid, &sm.q[0][tid]);
    gload_lds16(src + tid + 512, &sm.q[0][tid + 512]);
    if (tid < 128) gload_lds4(e2b + sp * 1024 + 0 * 128 + tid, &lds_e2[0][tid]);
  }

  f16x8 zh[2][2];
#pragma unroll
  for (int mt = 0; mt < 2; ++mt) {
    int m = mb + mt * 16 + c16;
#pragma unroll
    for (int s = 0; s < 2; ++s) {
      const float* zp = z_e + (size_t)m * 64 + s * 32 + quad * 8;
      float4 fa = ((const float4*)zp)[0];
      float4 fb = ((const float4*)zp)[1];
      float v[8] = {fa.x, fa.y, fa.z, fa.w, fb.x, fb.y, fb.z, fb.w};
      union { f16x8 v8; unsigned short e[8]; } H;
#pragma unroll
      for (int j = 0; j < 8; ++j) H.e[j] = f2h(-2.0f * v[j]);
      zh[mt][s] = H.v8;
    }
  }

  unsigned int b1[2][4], b2[2][4];
#pragma unroll
  for (int mt = 0; mt < 2; ++mt)
#pragma unroll
    for (int r = 0; r < 4; ++r) { b1[mt][r] = 0xFFFFFFFFu; b2[mt][r] = 0xFFFFFFFFu; }

  const int swz0 = ((quad + c16) & 7) * 16;
  const int swz1 = ((quad + 4 + c16) & 7) * 16;

  __syncthreads();

  int cur = 0;
  for (int c = 0; c < NCHB; ++c) {
    if (c + 1 < NCHB) {
      const int nb = cur ^ 1;
      const uint4* src = (const uint4*)(img + (size_t)(sp * NCHB + c + 1) * CH_BYTES);
      gload_lds16(src + tid, &sm.q[nb][tid]);
      gload_lds16(src + tid + 512, &sm.q[nb][tid + 512]);
      if (tid < 128) gload_lds4(e2b + sp * 1024 + (c + 1) * 128 + tid, &lds_e2[nb][tid]);
    }

#pragma unroll 1
    for (int t = 0; t < 8; ++t) {
      const char* hb = sm.raw[cur] + (t * 16 + c16) * 128;
      f16x8 Bh0 = *(const f16x8*)(hb + swz0);
      f16x8 Bh1 = *(const f16x8*)(hb + swz1);
      float e2v = lds_e2[cur][t * 16 + c16];
      unsigned int tid8 = (unsigned int)(sp * 64 + c * 8 + t);
      f32x4 cvec = {e2v, e2v, e2v, e2v};

#pragma unroll
      for (int mt = 0; mt < 2; ++mt) {
        f32x4 acc;
        acc = __builtin_amdgcn_mfma_f32_16x16x32_f16(zh[mt][0], Bh0, cvec, 0, 0, 0);
        acc = __builtin_amdgcn_mfma_f32_16x16x32_f16(zh[mt][1], Bh1, acc, 0, 0, 0);
#pragma unroll
        for (int r = 0; r < 4; ++r) {
          unsigned int key = (__float_as_uint(acc[r]) & 0xFFFFFF00u) | tid8;
          b2[mt][r] = med3_u32(b1[mt][r], b2[mt][r], key);
          b1[mt][r] = umin_(b1[mt][r], key);
        }
      }
    }
    __syncthreads();
    cur ^= 1;
  }

  __syncthreads();
  {
#pragma unroll
    for (int mt = 0; mt < 2; ++mt)
#pragma unroll
      for (int r = 0; r < 4; ++r) {
        int lr = wave * 32 + mt * 16 + quad * 4 + r;
        sm.cand[lr * 33 + c16 * 2 + 0] = b1[mt][r];
        sm.cand[lr * 33 + c16 * 2 + 1] = b2[mt][r];
      }
  }
  __syncthreads();
  if (tid < 256) {
    unsigned int kk[4] = {0xFFFFFFFFu, 0xFFFFFFFFu, 0xFFFFFFFFu, 0xFFFFFFFFu};
    unsigned int vv[4] = {0, 0, 0, 0};
    for (int j = 0; j < 32; ++j) {
      unsigned int key = sm.cand[tid * 33 + j];
      if (key < kk[3]) {
        kk[3] = key;
        vv[3] = (key & 0xFFu) * 16 + (unsigned int)(j >> 1);
        for (int p = 3; p > 0; --p)
          if (kk[p] < kk[p - 1]) {
            unsigned int a = kk[p]; kk[p] = kk[p - 1]; kk[p - 1] = a;
            unsigned int b = vv[p]; vv[p] = vv[p - 1]; vv[p - 1] = b;
          }
      }
    }
    int grow = rb * 256 + tid;
#pragma unroll
    for (int i = 0; i < 4; ++i)
      cand64[(size_t)grow * 16 + sp * 4 + i] = ((u64)kk[i] << 32) | (u64)vv[i];
  }
}

__device__ __forceinline__ void pick_scan4(const u64* __restrict__ cand64,
                                           int row, int part, u64& s1, u64& s2) {
  s1 = ~0ull; s2 = ~0ull;
  const u64* cp = cand64 + (size_t)row * 16 + part * 4;
#pragma unroll
  for (int j = 0; j < 4; ++j) {
    u64 v = cp[j];
    if (v < s1) { s2 = s1; s1 = v; }
    else if (v < s2) s2 = v;
  }
#pragma unroll
  for (int m = 1; m <= 2; m <<= 1) {
    u64 o1 = __shfl_xor(s1, m);
    u64 o2 = __shfl_xor(s2, m);
    u64 hi  = s1 > o1 ? s1 : o1;
    u64 lo2 = s2 < o2 ? s2 : o2;
    s1 = s1 < o1 ? s1 : o1;
    s2 = hi < lo2 ? hi : lo2;
  }
}

__device__ __forceinline__ int pick_exact16(const float* __restrict__ z_e,
                                            const float* __restrict__ cb,
                                            const float* __restrict__ e2,
                                            const u64* __restrict__ cand64,
                                            int row, int lane16) {
  const int k = (int)(unsigned int)(cand64[(size_t)row * 16 + lane16] & 0xFFFFFFFFu);
  const float4* zr = (const float4*)(z_e + (size_t)row * 64);
  float4 z4[16];
#pragma unroll
  for (int j = 0; j < 16; ++j) z4[j] = zr[j];
  float z2 = exact_z2(z4);
  float d = exact_dist(z4, z2, cb, e2, k);
  u64 kk = ((u64)ford(d) << 32) | (unsigned int)k;
#pragma unroll
  for (int m = 1; m <= 8; m <<= 1) {
    u64 o = __shfl_xor(kk, m);
    kk = o < kk ? o : kk;
  }
  return (int)(unsigned int)(kk & 0xFFFFFFFFu);
}

__global__ __launch_bounds__(256)
void pick_kernel(const float* __restrict__ z_e, const float* __restrict__ cb,
                 const float* __restrict__ e2, const u64* __restrict__ cand64,
                 float* __restrict__ out) {
  __shared__ int list[64];
  __shared__ int lcnt;
  const int tid = threadIdx.x;
  const int R0  = blockIdx.x * 64;
  if (tid == 0) lcnt = 0;
  __syncthreads();

  {
    const int row = R0 + (tid >> 2);
    u64 s1, s2;
    pick_scan4(cand64, row, tid & 3, s1, s2);
    if ((tid & 3) == 0) {
      unsigned int key1 = (unsigned int)(s1 >> 32) & 0xFFFFFF00u;
      unsigned int key2 = (unsigned int)(s2 >> 32) & 0xFFFFFF00u;
      if ((key2 - key1) >= 2048u) {
        out[OFF_IDX + row] = (float)(unsigned int)(s1 & 0xFFFFFFFFu);
      } else {
        list[atomicAdd(&lcnt, 1)] = row - R0;
      }
    }
  }
  __syncthreads();

  const int n = lcnt;
  const int lane16 = tid & 15;
  for (int g = tid >> 4; g < n; g += 16) {
    const int row = R0 + list[g];
    int bk = pick_exact16(z_e, cb, e2, cand64, row, lane16);
    if (lane16 == 0) out[OFF_IDX + row] = (float)bk;
  }
}

__global__ __launch_bounds__(256)
void zq_kernel(const float* __restrict__ z_e, const float* __restrict__ cb,
               float* __restrict__ out, double* __restrict__ partials) {
  const int tid = threadIdx.x;
  const int t   = blockIdx.x * 256 + tid;
  const int m   = t >> 4, seg = t & 15;

  int k = (int)out[OFF_IDX + m];
  float4 q = *(const float4*)(cb + (size_t)k * 64 + seg * 4);
  float4 z = *(const float4*)(z_e + (size_t)m * 64 + seg * 4);

  ((float4*)out)[(size_t)m * 16 + seg] = q;
  float* d1 = out + OFF_ZQ + (size_t)m * 64 + seg * 4;
  ((float2*)d1)[0] = make_float2(q.x, q.y);
  ((float2*)d1)[1] = make_float2(q.z, q.w);

  float dx = z.x - q.x, dy = z.y - q.y, dz = z.z - q.z, dw = z.w - q.w;
  double csum = (double)dx * dx + (double)dy * dy + (double)dz * dz + (double)dw * dw;
#pragma unroll
  for (int off = 32; off > 0; off >>= 1) csum += __shfl_down(csum, off);
  if ((tid & 63) == 0) partials[blockIdx.x * 4 + (tid >> 6)] = csum;
}

// ---------------------------------------------------------------------------
// K5: vq_loss (sum of n partials) + perplexity — 1024 threads
// ---------------------------------------------------------------------------
__global__ void finalize_kernel(const float* __restrict__ ema,
                                const double* __restrict__ partials, int n,
                                float* __restrict__ out) {
  __shared__ double red[1024];
  const int t = threadIdx.x;

  double cs = 0.0;
  for (int i = t; i < n; i += 1024) cs += partials[i];
  red[t] = cs;
  __syncthreads();
  for (int off = 512; off > 0; off >>= 1) {
    if (t < off) red[t] += red[t + off];
    __syncthreads();
  }
  double commit = red[0];
  __syncthreads();

  double s = 0.0;
  for (int i = t; i < K_CODES; i += 1024) s += (double)(ema[i] + 1e-10f);
  red[t] = s;
  __syncthreads();
  for (int off = 512; off > 0; off >>= 1) {
    if (t < off) red[t] += red[t + off];
    __syncthreads();
  }
  double S = red[0];
  __syncthreads();

  double h = 0.0;
  for (int i = t; i < K_CODES; i += 1024) {
    float p = (float)((ema[i] + 1e-10f) / (float)S);
    h += (double)(p * logf(p));
  }
  red[t] = h;
  __syncthreads();
  for (int off = 512; off > 0; off >>= 1) {
    if (t < off) red[t] += red[t + off];
    __syncthreads();
  }

  if (t == 0) {
    out[OFF_SCAL]     = 0.25f * (float)(commit / (double)((size_t)M_ROWS * (size_t)D_DIM));
    out[OFF_SCAL + 1] = expf((float)(-red[0]));
  }
}

extern "C" void kernel_launch(void* const* d_in, const int* in_sizes, int n_in,
                              void* d_out, int out_size, void* d_ws, size_t ws_size,
                              hipStream_t stream) {
  (void)in_sizes; (void)n_in; (void)out_size;
  const float* z_e = (const float*)d_in[0];
  const float* cb  = (const float*)d_in[1];
  const float* ema = (const float*)d_in[2];
  float* out = (float*)d_out;

  // ws layout: e2 @0 (16K) | e2b @16K (16K) | partials @32K (128K) | img @160K (512K)
  float*  e2       = (float*)d_ws;
  float*  e2b      = (float*)((char*)d_ws + 16384);
  double* partials = (double*)((char*)d_ws + 32768);
  const size_t fused_need = 163840 + 524288;            // 672 KB

  if (ws_size >= fused_need) {
    char* img = (char*)d_ws + 163840;                   // img in ws: no alias with z_q_st
    prep_kernel<<<(K_CODES * D_DIM / 4) / 256, 256, 0, stream>>>(cb, img, e2, e2b);
    vq_full_kernel<<<M_ROWS / 128, 512, 0, stream>>>(z_e, img, e2b, cb, e2, out, partials);
    finalize_kernel<<<1, 1024, 0, stream>>>(ema, partials, M_ROWS / 128, out);
  } else {
    // fallback: round-8 three-kernel path; img + cand64 scratched inside d_out
    char* img = (char*)d_out + IMG_OFF;
    u64* cand64 = (u64*)((char*)d_out + CANDB_OFF);
    prep_kernel<<<(K_CODES * D_DIM / 4) / 256, 256, 0, stream>>>(cb, img, e2, e2b);
    vq_mfma_kernel<<<(M_ROWS / 256) * NSPLIT, 512, 0, stream>>>(z_e, img, e2b, cand64);
    pick_kernel<<<M_ROWS / 64, 256, 0, stream>>>(z_e, cb, e2, cand64, out);
    zq_kernel<<<M_ROWS * 16 / 256, 256, 0, stream>>>(z_e, cb, out, partials);
    finalize_kernel<<<1, 1024, 0, stream>>>(ema, partials, 16384, out);
  }
}